// Round 1
// baseline (1227.816 us; speedup 1.0000x reference)
//
#include <hip/hip_runtime.h>

// IDWT_2D Haar: B=4, Ct=256 (C=64 groups x 4 subbands), H=W=256 -> out [4,256,512,512]
// y[b, g*4+j, 2h+a, 2w+c] = (sum_n x[b, n*64+g, h, w]) * filters[j,a,c]
//
// Pure HBM-bound scatter: 256 MiB in + 1 GiB out => ~215 us floor at 6.3 TB/s.

#define B   4
#define C   64      // wavelet groups
#define H   256
#define W   256
#define W4  (W / 4) // 4 w-positions per thread

__global__ __launch_bounds__(256) void idwt2d_haar_kernel(
    const float* __restrict__ x,     // [B, 4*C, H, W]
    const float* __restrict__ filt,  // [4, 2, 2]
    float* __restrict__ y)           // [B, 4*C, 2H, 2W]
{
    const int tid = blockIdx.x * 256 + threadIdx.x;
    // tid = ((b*C + g)*H + h)*W4 + w4
    const int w4 = tid & (W4 - 1);
    const int h  = (tid >> 6) & (H - 1);
    const int g  = (tid >> 14) & (C - 1);
    const int b  = tid >> 20;

    const int w = w4 << 2;  // starting w (4 consecutive)

    // input: x[b, n*C+g, h, w..w+3], n-stride = C*H*W
    const int nstride = C * H * W;
    const int in_base = (((b * (4 * C)) + g) * H + h) * W + w;
    const float4 x0 = *(const float4*)(x + in_base);
    const float4 x1 = *(const float4*)(x + in_base + nstride);
    const float4 x2 = *(const float4*)(x + in_base + 2 * nstride);
    const float4 x3 = *(const float4*)(x + in_base + 3 * nstride);

    float4 s;
    s.x = (x0.x + x1.x) + (x2.x + x3.x);
    s.y = (x0.y + x1.y) + (x2.y + x3.y);
    s.z = (x0.z + x1.z) + (x2.z + x3.z);
    s.w = (x0.w + x1.w) + (x2.w + x3.w);

    // output: y[b, g*4+j, 2h+a, 2w + 0..7]
    const int out_ch0 = b * (4 * C) + g * 4;  // channel of j=0
    const int row0 = 2 * h;
    const int col0 = 2 * w;

#pragma unroll
    for (int j = 0; j < 4; ++j) {
        const float fj00 = filt[j * 4 + 0];
        const float fj01 = filt[j * 4 + 1];
        const float fj10 = filt[j * 4 + 2];
        const float fj11 = filt[j * 4 + 3];
        const int ch_base = ((out_ch0 + j) * (2 * H)) * (2 * W);
#pragma unroll
        for (int a = 0; a < 2; ++a) {
            const float f0 = (a == 0) ? fj00 : fj10;
            const float f1 = (a == 0) ? fj01 : fj11;
            float4 o0, o1;
            o0.x = s.x * f0; o0.y = s.x * f1;
            o0.z = s.y * f0; o0.w = s.y * f1;
            o1.x = s.z * f0; o1.y = s.z * f1;
            o1.z = s.w * f0; o1.w = s.w * f1;
            const int off = ch_base + (row0 + a) * (2 * W) + col0;
            *(float4*)(y + off)     = o0;
            *(float4*)(y + off + 4) = o1;
        }
    }
}

extern "C" void kernel_launch(void* const* d_in, const int* in_sizes, int n_in,
                              void* d_out, int out_size, void* d_ws, size_t ws_size,
                              hipStream_t stream) {
    const float* x    = (const float*)d_in[0];  // [4, 256, 256, 256] fp32
    const float* filt = (const float*)d_in[1];  // [4, 2, 2] fp32
    float* y = (float*)d_out;                   // [4, 256, 512, 512] fp32

    const int total_threads = B * C * H * W4;   // 4,194,304
    const int block = 256;
    const int grid = total_threads / block;     // 16384
    idwt2d_haar_kernel<<<grid, block, 0, stream>>>(x, filt, y);
}